// Round 2
// baseline (1278.483 us; speedup 1.0000x reference)
//
#include <hip/hip_runtime.h>
#include <hip/hip_bf16.h>
#include <math.h>

// SparseFeedForward: B=4 L=2048 H=16 Dh=256 M=1024, D=4096, rows=8192
// out[r, perm[h*256+d]] = sum_m gelu( sum_k x[r, perm[h*256+k]] * up[h,k,m] ) * down[h,m,d]
//
// Structure:
//   1) transpose_cvt: up(h,d,m)->upT(h,m,d) bf16, down(h,m,d)->downT(h,d,m) bf16 (ws, 16.8MB)
//   2) ffn_kernel: 2048 blocks = 128 row-tiles x 16 heads, XCD-chunk swizzled.
//      Per block: gather+cast 64x256 X tile into XOR-swizzled LDS; loop 8x 128-m chunks:
//      GEMM1 (swapped operands -> H^T frags) -> gelu in-register -> swizzled sH ->
//      GEMM2 accumulate fp32; scatter-store epilogue via perm.

typedef __attribute__((ext_vector_type(8))) short bf16x8;
typedef __attribute__((ext_vector_type(4))) float f32x4;

__device__ __forceinline__ unsigned short f2bf(float f) {
    unsigned int u = __builtin_bit_cast(unsigned int, f);
    u = (u + 0x7FFFu + ((u >> 16) & 1u)) >> 16;   // RNE
    return (unsigned short)u;
}

__device__ __forceinline__ float gelu_exact(float v) {
    return 0.5f * v * (1.0f + erff(v * 0.70710678118654752f));
}

// dst[h][c][r] = bf16(src[h][r][c])   (per-head transpose-convert)
__global__ __launch_bounds__(256) void transpose_cvt_kernel(
        const float* __restrict__ src, unsigned short* __restrict__ dst,
        int R, int C) {
    int tilesC = C >> 6;
    int tiles = tilesC * (R >> 6);
    int h = blockIdx.x / tiles;
    int t = blockIdx.x % tiles;
    int r0 = (t / tilesC) << 6;
    int c0 = (t % tilesC) << 6;
    const float* s = src + (size_t)h * R * C;
    unsigned short* d = dst + (size_t)h * R * C;
    __shared__ float tl[64][65];
    int col = threadIdx.x & 63;
    int rr = threadIdx.x >> 6;
    #pragma unroll
    for (int i = 0; i < 16; ++i) {
        int row = (i << 2) + rr;
        tl[row][col] = s[(size_t)(r0 + row) * C + (c0 + col)];
    }
    __syncthreads();
    #pragma unroll
    for (int i = 0; i < 16; ++i) {
        int row = (i << 2) + rr;
        d[(size_t)(c0 + row) * R + (r0 + col)] = f2bf(tl[col][row]);
    }
}

__global__ __launch_bounds__(256, 2) void ffn_kernel(
    const float* __restrict__ x, const int* __restrict__ perm,
    const unsigned short* __restrict__ upT,    // [16][1024 m][256 d] bf16
    const unsigned short* __restrict__ downT,  // [16][256 d][1024 m] bf16
    float* __restrict__ out)
{
    __shared__ unsigned char sA[64 * 512];   // X tile [64 r][256 k] bf16, XOR-swizzled (32 cells/row)
    __shared__ unsigned char sH[64 * 256];   // hidden [64 r][128 m] bf16, XOR-swizzled (16 cells/row)

    int tid = threadIdx.x;
    int lane = tid & 63;
    int wave = tid >> 6;
    int l15 = lane & 15;
    int lq = lane >> 4;

    // XCD-chunk swizzle: 2048 blocks, 8 XCDs -> 256-block contiguous chunks per XCD,
    // head-major within chunk so each XCD's resident blocks share <=2 heads' weights (L2-fit).
    int bid = blockIdx.x;
    int nb = ((bid & 7) << 8) + (bid >> 3);
    int head = nb >> 7;
    int row0 = (nb & 127) << 6;

    const int* ph = perm + (head << 8);

    // ---- stage A: gathered+permuted X rows, fp32->bf16, swizzled LDS ----
    for (int i = 0; i < 8; ++i) {
        int idx = tid + (i << 8);            // 0..2047 cells of 16B
        int r = idx >> 5;                    // row 0..63
        int s = idx & 31;                    // swizzled slot
        int k0 = (s ^ (r & 31)) << 3;        // original k of this cell
        const float* xr = x + ((size_t)(row0 + r) << 12);
        int4 p0 = *(const int4*)(ph + k0);
        int4 p1 = *(const int4*)(ph + k0 + 4);
        unsigned int w0 = f2bf(xr[p0.x]) | ((unsigned int)f2bf(xr[p0.y]) << 16);
        unsigned int w1 = f2bf(xr[p0.z]) | ((unsigned int)f2bf(xr[p0.w]) << 16);
        unsigned int w2 = f2bf(xr[p1.x]) | ((unsigned int)f2bf(xr[p1.y]) << 16);
        unsigned int w3 = f2bf(xr[p1.z]) | ((unsigned int)f2bf(xr[p1.w]) << 16);
        *(uint4*)(sA + r * 512 + (s << 4)) = make_uint4(w0, w1, w2, w3);
    }
    __syncthreads();

    int wr = wave & 1;   // owns row-blocks {2wr, 2wr+1} in GEMM1
    int wm = wave >> 1;  // owns m-blocks {4wm..4wm+3} in GEMM1

    f32x4 acc[4][4] = {};   // [rb][cb] out rows x d accum

    for (int mc = 0; mc < 8; ++mc) {
        int m0 = mc << 7;   // 128-wide M chunk

        // ---- GEMM1: H^T fragments = mfma(W1-frag, X-frag) ----
        f32x4 hacc[4][2] = {};
        #pragma unroll
        for (int ks = 0; ks < 8; ++ks) {
            bf16x8 xb[2];
            #pragma unroll
            for (int j = 0; j < 2; ++j) {
                int r = ((2 * wr + j) << 4) + l15;
                int bo = r * 512 + ((((ks << 6) + (lq << 4))) ^ ((r & 31) << 4));
                xb[j] = *(const bf16x8*)(sA + bo);
            }
            #pragma unroll
            for (int i = 0; i < 4; ++i) {
                int m = m0 + (((wm << 2) + i) << 4) + l15;
                int kk = (ks << 5) + (lq << 3);
                bf16x8 wf = *(const bf16x8*)(upT + ((size_t)((head << 10) + m) << 8) + kk);
                #pragma unroll
                for (int j = 0; j < 2; ++j)
                    hacc[i][j] = __builtin_amdgcn_mfma_f32_16x16x32_bf16(wf, xb[j], hacc[i][j], 0, 0, 0);
            }
        }
        // gelu + write hidden (lane holds 4 consecutive m for fixed row -> b64 write)
        #pragma unroll
        for (int i = 0; i < 4; ++i) {
            #pragma unroll
            for (int j = 0; j < 2; ++j) {
                int r = ((2 * wr + j) << 4) + l15;
                int mbyte = (((wm << 2) + i) << 5) + (lq << 3);
                float g0 = gelu_exact(hacc[i][j][0]);
                float g1 = gelu_exact(hacc[i][j][1]);
                float g2 = gelu_exact(hacc[i][j][2]);
                float g3 = gelu_exact(hacc[i][j][3]);
                uint2 wv;
                wv.x = f2bf(g0) | ((unsigned int)f2bf(g1) << 16);
                wv.y = f2bf(g2) | ((unsigned int)f2bf(g3) << 16);
                *(uint2*)(sH + r * 256 + (mbyte ^ ((r & 15) << 4))) = wv;
            }
        }
        __syncthreads();

        // ---- GEMM2: acc += H(64x128) * W2chunk(128x256), W2 frags from L2 ----
        #pragma unroll
        for (int ks = 0; ks < 4; ++ks) {
            bf16x8 ha[4];
            #pragma unroll
            for (int rb = 0; rb < 4; ++rb) {
                int r = (rb << 4) + l15;
                int bo = r * 256 + ((((ks << 6) + (lq << 4))) ^ ((r & 15) << 4));
                ha[rb] = *(const bf16x8*)(sH + bo);
            }
            #pragma unroll
            for (int i = 0; i < 4; ++i) {
                int d = (((wave << 2) + i) << 4) + l15;
                int mg = m0 + (ks << 5) + (lq << 3);
                bf16x8 wf = *(const bf16x8*)(downT + ((size_t)((head << 8) + d) << 10) + mg);
                #pragma unroll
                for (int rb = 0; rb < 4; ++rb)
                    acc[rb][i] = __builtin_amdgcn_mfma_f32_16x16x32_bf16(ha[rb], wf, acc[rb][i], 0, 0, 0);
            }
        }
        __syncthreads();
    }

    // ---- epilogue: scatter fp32 stores via perm ----
    int pd[4];
    #pragma unroll
    for (int i = 0; i < 4; ++i)
        pd[i] = ph[(((wave << 2) + i) << 4) + l15];
    #pragma unroll
    for (int rb = 0; rb < 4; ++rb) {
        #pragma unroll
        for (int i = 0; i < 4; ++i) {
            int r0g = row0 + (rb << 4) + (lq << 2);
            #pragma unroll
            for (int e = 0; e < 4; ++e)
                out[((size_t)(r0g + e) << 12) + pd[i]] = acc[rb][i][e];
        }
    }
}

extern "C" void kernel_launch(void* const* d_in, const int* in_sizes, int n_in,
                              void* d_out, int out_size, void* d_ws, size_t ws_size,
                              hipStream_t stream) {
    const float* x    = (const float*)d_in[0];   // (4,2048,4096) f32
    const float* up   = (const float*)d_in[1];   // (16,256,1024) f32
    const float* down = (const float*)d_in[2];   // (16,1024,256) f32
    const int*   perm = (const int*)d_in[3];     // (4096,) i32
    float* out = (float*)d_out;

    unsigned short* upT   = (unsigned short*)d_ws;                    // 8 MB
    unsigned short* downT = upT + (size_t)16 * 1024 * 256;            // 8 MB

    // up (16,256,1024) -> upT (16,1024,256)
    transpose_cvt_kernel<<<16 * 4 * 16, 256, 0, stream>>>(up, upT, 256, 1024);
    // down (16,1024,256) -> downT (16,256,1024)
    transpose_cvt_kernel<<<16 * 16 * 4, 256, 0, stream>>>(down, downT, 1024, 256);

    ffn_kernel<<<2048, 256, 0, stream>>>(x, perm, upT, downT, out);
}

// Round 3
// 737.235 us; speedup vs baseline: 1.7342x; 1.7342x over previous
//
#include <hip/hip_runtime.h>
#include <hip/hip_bf16.h>
#include <math.h>

// SparseFeedForward: B=4 L=2048 H=16 Dh=256 M=1024, D=4096, rows=8192
// out[r, perm[h*256+d]] = sum_m gelu( sum_k x[r, perm[h*256+k]] * up[h,k,m] ) * down[h,m,d]
//
// v3 structure (round-2 counters showed gather/scatter line-amplification = 2.1 GB HBM):
//   1) transpose_cvt: up->upT(h,m,k) bf16, down->downT(h,d,m) bf16    (ws, 16.8 MB)
//   2) permute_x: xP[r][j] = bf16(x[r][perm[j]]) via per-row LDS gather -> coalesced (67 MB)
//   3) ffn: per (64-row, head) block: linear-coalesced xP stage -> GEMM1 -> gelu -> GEMM2,
//      coalesced yP write (permuted layout, f32 if ws allows else bf16)
//   4) unpermute: out[r][perm[j]] = yP[r][j] via per-row LDS scatter -> coalesced out

typedef __attribute__((ext_vector_type(8))) short bf16x8;
typedef __attribute__((ext_vector_type(4))) float f32x4;

__device__ __forceinline__ unsigned short f2bf(float f) {
    unsigned int u = __builtin_bit_cast(unsigned int, f);
    u = (u + 0x7FFFu + ((u >> 16) & 1u)) >> 16;   // RNE
    return (unsigned short)u;
}
__device__ __forceinline__ float bf2f(unsigned short u) {
    return __builtin_bit_cast(float, ((unsigned int)u) << 16);
}
__device__ __forceinline__ float gelu_exact(float v) {
    return 0.5f * v * (1.0f + erff(v * 0.70710678118654752f));
}

// dst[h][c][r] = bf16(src[h][r][c])   (per-head transpose-convert)
__global__ __launch_bounds__(256) void transpose_cvt_kernel(
        const float* __restrict__ src, unsigned short* __restrict__ dst,
        int R, int C) {
    int tilesC = C >> 6;
    int tiles = tilesC * (R >> 6);
    int h = blockIdx.x / tiles;
    int t = blockIdx.x % tiles;
    int r0 = (t / tilesC) << 6;
    int c0 = (t % tilesC) << 6;
    const float* s = src + (size_t)h * R * C;
    unsigned short* d = dst + (size_t)h * R * C;
    __shared__ float tl[64][65];
    int col = threadIdx.x & 63;
    int rr = threadIdx.x >> 6;
    #pragma unroll
    for (int i = 0; i < 16; ++i) {
        int row = (i << 2) + rr;
        tl[row][col] = s[(size_t)(r0 + row) * C + (c0 + col)];
    }
    __syncthreads();
    #pragma unroll
    for (int i = 0; i < 16; ++i) {
        int row = (i << 2) + rr;
        d[(size_t)(c0 + row) * R + (r0 + col)] = f2bf(tl[col][row]);
    }
}

// xP[r][j] = bf16(x[r][perm[j]]) — 8 rows/block, LDS row gather, coalesced both sides
__global__ __launch_bounds__(256) void permute_x_kernel(
        const float* __restrict__ x, const int* __restrict__ perm,
        unsigned short* __restrict__ xP) {
    __shared__ float row[4096];
    __shared__ int sperm[4096];
    int tid = threadIdx.x;
    #pragma unroll
    for (int i = 0; i < 16; ++i) sperm[(i << 8) + tid] = perm[(i << 8) + tid];
    size_t r0 = (size_t)blockIdx.x << 3;
    for (int rr = 0; rr < 8; ++rr) {
        size_t r = r0 + rr;
        __syncthreads();   // also covers sperm readiness at rr=0
        const float4* xr = (const float4*)(x + (r << 12));
        #pragma unroll
        for (int i = 0; i < 4; ++i)
            *(float4*)(row + (((i << 8) + tid) << 2)) = xr[(i << 8) + tid];
        __syncthreads();
        alignas(16) unsigned short tmp[16];
        int j0 = tid << 4;
        #pragma unroll
        for (int i = 0; i < 16; ++i) tmp[i] = f2bf(row[sperm[j0 + i]]);
        *(uint4*)(xP + (r << 12) + j0) = *(const uint4*)tmp;
        *(uint4*)(xP + (r << 12) + j0 + 8) = *(const uint4*)(tmp + 8);
    }
}

// out[r][perm[j]] = yP[r][j] — scatter into LDS row, write out coalesced
template<int F32>
__global__ __launch_bounds__(256) void unpermute_kernel(
        const void* __restrict__ yPv, const int* __restrict__ perm,
        float* __restrict__ out) {
    __shared__ float row[4096];
    __shared__ int sperm[4096];
    int tid = threadIdx.x;
    #pragma unroll
    for (int i = 0; i < 16; ++i) sperm[(i << 8) + tid] = perm[(i << 8) + tid];
    size_t r0 = (size_t)blockIdx.x << 3;
    for (int rr = 0; rr < 8; ++rr) {
        size_t r = r0 + rr;
        __syncthreads();
        if (F32) {
            const float4* yr = (const float4*)((const float*)yPv + (r << 12));
            #pragma unroll
            for (int i = 0; i < 4; ++i) {
                float4 v = yr[(i << 8) + tid];
                int j = ((i << 8) + tid) << 2;
                row[sperm[j]]     = v.x;
                row[sperm[j + 1]] = v.y;
                row[sperm[j + 2]] = v.z;
                row[sperm[j + 3]] = v.w;
            }
        } else {
            const uint2* yr = (const uint2*)((const unsigned short*)yPv + (r << 12));
            #pragma unroll
            for (int i = 0; i < 4; ++i) {
                uint2 v = yr[(i << 8) + tid];
                int j = ((i << 8) + tid) << 2;
                row[sperm[j]]     = bf2f((unsigned short)(v.x & 0xffffu));
                row[sperm[j + 1]] = bf2f((unsigned short)(v.x >> 16));
                row[sperm[j + 2]] = bf2f((unsigned short)(v.y & 0xffffu));
                row[sperm[j + 3]] = bf2f((unsigned short)(v.y >> 16));
            }
        }
        __syncthreads();
        float4* orow = (float4*)(out + (r << 12));
        #pragma unroll
        for (int i = 0; i < 4; ++i)
            orow[(i << 8) + tid] = *(const float4*)(row + (((i << 8) + tid) << 2));
    }
}

template<int YPF32>
__global__ __launch_bounds__(256, 3) void ffn_kernel(
    const unsigned short* __restrict__ xP,     // [8192][4096] bf16, permuted cols
    const unsigned short* __restrict__ upT,    // [16][1024 m][256 k] bf16
    const unsigned short* __restrict__ downT,  // [16][256 d][1024 m] bf16
    void* __restrict__ yPv)                    // [8192][4096] f32 or bf16, permuted cols
{
    __shared__ unsigned char sA[64 * 512];   // X tile [64 r][256 k] bf16, XOR-swizzled (32 cells/row)
    __shared__ unsigned char sH[64 * 256];   // hidden [64 r][128 m] bf16, XOR-swizzled (16 cells/row)

    int tid = threadIdx.x;
    int lane = tid & 63;
    int wave = tid >> 6;
    int l15 = lane & 15;
    int lq = lane >> 4;

    // XCD-chunk swizzle: 2048 blocks, 8 XCDs; head-major within chunk (<=2 heads/XCD in L2)
    int bid = blockIdx.x;
    int nb = ((bid & 7) << 8) + (bid >> 3);
    int head = nb >> 7;
    int row0 = (nb & 127) << 6;

    // ---- stage A: linear coalesced read from xP head-slice -> swizzled LDS ----
    #pragma unroll
    for (int i = 0; i < 8; ++i) {
        int idx = tid + (i << 8);            // 0..2047 cells of 16B
        int r = idx >> 5;                    // row 0..63
        int s = idx & 31;                    // linear source cell
        const unsigned short* src = xP + (((size_t)(row0 + r)) << 12) + (head << 8) + (s << 3);
        bf16x8 v = *(const bf16x8*)src;
        *(bf16x8*)(sA + r * 512 + ((s ^ (r & 31)) << 4)) = v;
    }
    __syncthreads();

    int wr = wave & 1;   // owns row-blocks {2wr, 2wr+1} in GEMM1
    int wm = wave >> 1;  // owns m-blocks {4wm..4wm+3} in GEMM1

    f32x4 acc[4][4] = {};   // [rb][cb] out rows x d accum

    for (int mc = 0; mc < 8; ++mc) {
        int m0 = mc << 7;   // 128-wide M chunk

        // ---- GEMM1: H^T fragments = mfma(W1-frag, X-frag) ----
        f32x4 hacc[4][2] = {};
        #pragma unroll
        for (int ks = 0; ks < 8; ++ks) {
            bf16x8 xb[2];
            #pragma unroll
            for (int j = 0; j < 2; ++j) {
                int r = ((2 * wr + j) << 4) + l15;
                int bo = r * 512 + ((((ks << 6) + (lq << 4))) ^ ((r & 31) << 4));
                xb[j] = *(const bf16x8*)(sA + bo);
            }
            #pragma unroll
            for (int i = 0; i < 4; ++i) {
                int m = m0 + (((wm << 2) + i) << 4) + l15;
                int kk = (ks << 5) + (lq << 3);
                bf16x8 wf = *(const bf16x8*)(upT + ((size_t)((head << 10) + m) << 8) + kk);
                #pragma unroll
                for (int j = 0; j < 2; ++j)
                    hacc[i][j] = __builtin_amdgcn_mfma_f32_16x16x32_bf16(wf, xb[j], hacc[i][j], 0, 0, 0);
            }
        }
        // gelu + write hidden (lane holds 4 consecutive m for fixed row -> b64 write)
        #pragma unroll
        for (int i = 0; i < 4; ++i) {
            #pragma unroll
            for (int j = 0; j < 2; ++j) {
                int r = ((2 * wr + j) << 4) + l15;
                int mbyte = (((wm << 2) + i) << 5) + (lq << 3);
                float g0 = gelu_exact(hacc[i][j][0]);
                float g1 = gelu_exact(hacc[i][j][1]);
                float g2 = gelu_exact(hacc[i][j][2]);
                float g3 = gelu_exact(hacc[i][j][3]);
                uint2 wv;
                wv.x = f2bf(g0) | ((unsigned int)f2bf(g1) << 16);
                wv.y = f2bf(g2) | ((unsigned int)f2bf(g3) << 16);
                *(uint2*)(sH + r * 256 + (mbyte ^ ((r & 15) << 4))) = wv;
            }
        }
        __syncthreads();

        // ---- GEMM2: acc += H(64x128) * W2chunk(128x256), W2 frags from L2 ----
        #pragma unroll
        for (int ks = 0; ks < 4; ++ks) {
            bf16x8 ha[4];
            #pragma unroll
            for (int rb = 0; rb < 4; ++rb) {
                int r = (rb << 4) + l15;
                int bo = r * 256 + ((((ks << 6) + (lq << 4))) ^ ((r & 15) << 4));
                ha[rb] = *(const bf16x8*)(sH + bo);
            }
            #pragma unroll
            for (int i = 0; i < 4; ++i) {
                int d = (((wave << 2) + i) << 4) + l15;
                int mg = m0 + (ks << 5) + (lq << 3);
                bf16x8 wf = *(const bf16x8*)(downT + ((size_t)((head << 8) + d) << 10) + mg);
                #pragma unroll
                for (int rb = 0; rb < 4; ++rb)
                    acc[rb][i] = __builtin_amdgcn_mfma_f32_16x16x32_bf16(ha[rb], wf, acc[rb][i], 0, 0, 0);
            }
        }
        __syncthreads();
    }

    // ---- epilogue: coalesced store into permuted-layout yP ----
    // acc[rb][i][e]: row = row0 + rb*16 + lq*4 + e, col = head*256 + (wave*4+i)*16 + l15
    if (YPF32) {
        float* yp = (float*)yPv;
        #pragma unroll
        for (int rb = 0; rb < 4; ++rb)
            #pragma unroll
            for (int i = 0; i < 4; ++i) {
                int rg = row0 + (rb << 4) + (lq << 2);
                int dc = (head << 8) + (((wave << 2) + i) << 4) + l15;
                #pragma unroll
                for (int e = 0; e < 4; ++e)
                    yp[((size_t)(rg + e) << 12) + dc] = acc[rb][i][e];
            }
    } else {
        unsigned short* yp = (unsigned short*)yPv;
        #pragma unroll
        for (int rb = 0; rb < 4; ++rb)
            #pragma unroll
            for (int i = 0; i < 4; ++i) {
                int rg = row0 + (rb << 4) + (lq << 2);
                int dc = (head << 8) + (((wave << 2) + i) << 4) + l15;
                #pragma unroll
                for (int e = 0; e < 4; ++e)
                    yp[((size_t)(rg + e) << 12) + dc] = f2bf(acc[rb][i][e]);
            }
    }
}

extern "C" void kernel_launch(void* const* d_in, const int* in_sizes, int n_in,
                              void* d_out, int out_size, void* d_ws, size_t ws_size,
                              hipStream_t stream) {
    const float* x    = (const float*)d_in[0];   // (4,2048,4096) f32
    const float* up   = (const float*)d_in[1];   // (16,256,1024) f32
    const float* down = (const float*)d_in[2];   // (16,1024,256) f32
    const int*   perm = (const int*)d_in[3];     // (4096,) i32
    float* out = (float*)d_out;

    const size_t W = (size_t)16 * 1024 * 256;    // weight elements per matrix
    const size_t XN = (size_t)8192 * 4096;       // activation elements
    unsigned short* upT   = (unsigned short*)d_ws;
    unsigned short* downT = upT + W;
    unsigned short* xP    = downT + W;
    void* yP = (void*)(xP + XN);
    size_t base_bytes = (2 * W + XN) * 2;        // 83.9 MB
    bool ypf32 = ws_size >= base_bytes + XN * 4; // need 218 MB for f32 yP, else bf16 (151 MB)

    transpose_cvt_kernel<<<16 * 4 * 16, 256, 0, stream>>>(up, upT, 256, 1024);
    transpose_cvt_kernel<<<16 * 16 * 4, 256, 0, stream>>>(down, downT, 1024, 256);
    permute_x_kernel<<<1024, 256, 0, stream>>>(x, perm, xP);

    if (ypf32) {
        ffn_kernel<1><<<2048, 256, 0, stream>>>(xP, upT, downT, yP);
        unpermute_kernel<1><<<1024, 256, 0, stream>>>(yP, perm, out);
    } else {
        ffn_kernel<0><<<2048, 256, 0, stream>>>(xP, upT, downT, yP);
        unpermute_kernel<0><<<1024, 256, 0, stream>>>(yP, perm, out);
    }
}

// Round 6
// 659.191 us; speedup vs baseline: 1.9395x; 1.1184x over previous
//
#include <hip/hip_runtime.h>
#include <hip/hip_bf16.h>
#include <math.h>

// SparseFeedForward: B=4 L=2048 H=16 Dh=256 M=1024, D=4096, rows=8192
// out[r, perm[h*256+d]] = sum_m gelu( sum_k x[r, perm[h*256+k]] * up[h,k,m] ) * down[h,m,d]
//
// v4: v3 + fast tanh-gelu (erff was ~35 VALU/elem -> ~6), batched W-frag loads + setprio
//     around MFMA clusters, and 4-row single-barrier permute/unpermute aux kernels.

typedef __attribute__((ext_vector_type(8))) short bf16x8;
typedef __attribute__((ext_vector_type(4))) float f32x4;

__device__ __forceinline__ unsigned short f2bf(float f) {
    unsigned int u = __builtin_bit_cast(unsigned int, f);
    u = (u + 0x7FFFu + ((u >> 16) & 1u)) >> 16;   // RNE
    return (unsigned short)u;
}
__device__ __forceinline__ float bf2f(unsigned short u) {
    return __builtin_bit_cast(float, ((unsigned int)u) << 16);
}

// gelu(x) ~= x * sigmoid(2*0.79788456*(x + 0.044715 x^3)); sigmoid via exp2/rcp.
// |err| ~1e-3 relative, << bf16 rounding already applied to inputs/weights.
__device__ __forceinline__ float gelu_fast(float x) {
    float x2 = x * x;
    float a = x * __builtin_fmaf(-0.10294437f, x2, -2.3022082f); // -2u*log2(e)
    return x * __builtin_amdgcn_rcpf(1.0f + __builtin_amdgcn_exp2f(a));
}

// dst[h][c][r] = bf16(src[h][r][c])   (per-head transpose-convert)
__global__ __launch_bounds__(256) void transpose_cvt_kernel(
        const float* __restrict__ src, unsigned short* __restrict__ dst,
        int R, int C) {
    int tilesC = C >> 6;
    int tiles = tilesC * (R >> 6);
    int h = blockIdx.x / tiles;
    int t = blockIdx.x % tiles;
    int r0 = (t / tilesC) << 6;
    int c0 = (t % tilesC) << 6;
    const float* s = src + (size_t)h * R * C;
    unsigned short* d = dst + (size_t)h * R * C;
    __shared__ float tl[64][65];
    int col = threadIdx.x & 63;
    int rr = threadIdx.x >> 6;
    #pragma unroll
    for (int i = 0; i < 16; ++i) {
        int row = (i << 2) + rr;
        tl[row][col] = s[(size_t)(r0 + row) * C + (c0 + col)];
    }
    __syncthreads();
    #pragma unroll
    for (int i = 0; i < 16; ++i) {
        int row = (i << 2) + rr;
        d[(size_t)(c0 + row) * R + (r0 + col)] = f2bf(tl[col][row]);
    }
}

// xP[r][j] = bf16(x[r][perm[j]]) — 4 rows/block, bf16 LDS rows, one barrier
__global__ __launch_bounds__(256) void permute_x_kernel(
        const float* __restrict__ x, const int* __restrict__ perm,
        unsigned short* __restrict__ xP) {
    __shared__ unsigned short rbf[4][4096];   // 32 KB
    __shared__ int sperm[4096];               // 16 KB
    int tid = threadIdx.x;
    #pragma unroll
    for (int i = 0; i < 16; ++i) sperm[(i << 8) + tid] = perm[(i << 8) + tid];
    size_t r0 = (size_t)blockIdx.x << 2;
    #pragma unroll
    for (int rr = 0; rr < 4; ++rr) {
        const float4* xr = (const float4*)(x + ((r0 + rr) << 12));
        #pragma unroll
        for (int i = 0; i < 4; ++i) {
            float4 v = xr[(i << 8) + tid];
            int j = ((i << 8) + tid) << 2;
            uint2 wv;
            wv.x = f2bf(v.x) | ((unsigned int)f2bf(v.y) << 16);
            wv.y = f2bf(v.z) | ((unsigned int)f2bf(v.w) << 16);
            *(uint2*)(&rbf[rr][j]) = wv;
        }
    }
    __syncthreads();
    #pragma unroll
    for (int rr = 0; rr < 4; ++rr) {
        alignas(16) unsigned short tmp[16];
        int j0 = tid << 4;
        #pragma unroll
        for (int i = 0; i < 16; ++i) tmp[i] = rbf[rr][sperm[j0 + i]];
        *(uint4*)(xP + ((r0 + rr) << 12) + j0) = *(const uint4*)tmp;
        *(uint4*)(xP + ((r0 + rr) << 12) + j0 + 8) = *(const uint4*)(tmp + 8);
    }
}

// out[r][perm[j]] = yP[r][j] — 4 rows/block, scatter into LDS, coalesced out
template<int F32>
__global__ __launch_bounds__(256) void unpermute_kernel(
        const void* __restrict__ yPv, const int* __restrict__ perm,
        float* __restrict__ out) {
    __shared__ float rows[4][4096];   // 64 KB
    __shared__ int sperm[4096];       // 16 KB
    int tid = threadIdx.x;
    #pragma unroll
    for (int i = 0; i < 16; ++i) sperm[(i << 8) + tid] = perm[(i << 8) + tid];
    size_t r0 = (size_t)blockIdx.x << 2;
    int j0 = tid << 4;
    // load values to regs first (no LDS dep), then barrier for sperm
    float vals[4][16];
    #pragma unroll
    for (int rr = 0; rr < 4; ++rr) {
        if (F32) {
            const float4* yr = (const float4*)((const float*)yPv + ((r0 + rr) << 12) + j0);
            #pragma unroll
            for (int i = 0; i < 4; ++i) {
                float4 v = yr[i];
                vals[rr][4 * i] = v.x; vals[rr][4 * i + 1] = v.y;
                vals[rr][4 * i + 2] = v.z; vals[rr][4 * i + 3] = v.w;
            }
        } else {
            const uint2* yr = (const uint2*)((const unsigned short*)yPv + ((r0 + rr) << 12) + j0);
            #pragma unroll
            for (int i = 0; i < 4; ++i) {
                uint2 v = yr[i];
                vals[rr][4 * i]     = bf2f((unsigned short)(v.x & 0xffffu));
                vals[rr][4 * i + 1] = bf2f((unsigned short)(v.x >> 16));
                vals[rr][4 * i + 2] = bf2f((unsigned short)(v.y & 0xffffu));
                vals[rr][4 * i + 3] = bf2f((unsigned short)(v.y >> 16));
            }
        }
    }
    __syncthreads();   // sperm ready
    #pragma unroll
    for (int rr = 0; rr < 4; ++rr)
        #pragma unroll
        for (int i = 0; i < 16; ++i)
            rows[rr][sperm[j0 + i]] = vals[rr][i];
    __syncthreads();
    #pragma unroll
    for (int rr = 0; rr < 4; ++rr) {
        float4* orow = (float4*)(out + ((r0 + rr) << 12));
        #pragma unroll
        for (int i = 0; i < 4; ++i)
            orow[(i << 8) + tid] = *(const float4*)(&rows[rr][((i << 8) + tid) << 2]);
    }
}

template<int YPF32>
__global__ __launch_bounds__(256, 3) void ffn_kernel(
    const unsigned short* __restrict__ xP,     // [8192][4096] bf16, permuted cols
    const unsigned short* __restrict__ upT,    // [16][1024 m][256 k] bf16
    const unsigned short* __restrict__ downT,  // [16][256 d][1024 m] bf16
    void* __restrict__ yPv)                    // [8192][4096] f32 or bf16, permuted cols
{
    __shared__ unsigned char sA[64 * 512];   // X tile [64 r][256 k] bf16, XOR-swizzled (32 cells/row)
    __shared__ unsigned char sH[64 * 256];   // hidden [64 r][128 m] bf16, XOR-swizzled (16 cells/row)

    int tid = threadIdx.x;
    int lane = tid & 63;
    int wave = tid >> 6;
    int l15 = lane & 15;
    int lq = lane >> 4;

    // XCD-chunk swizzle: 2048 blocks, 8 XCDs; head-major within chunk (<=2 heads/XCD in L2)
    int bid = blockIdx.x;
    int nb = ((bid & 7) << 8) + (bid >> 3);
    int head = nb >> 7;
    int row0 = (nb & 127) << 6;

    // ---- stage A: linear coalesced read from xP head-slice -> swizzled LDS ----
    #pragma unroll
    for (int i = 0; i < 8; ++i) {
        int idx = tid + (i << 8);            // 0..2047 cells of 16B
        int r = idx >> 5;                    // row 0..63
        int s = idx & 31;                    // linear source cell
        const unsigned short* src = xP + (((size_t)(row0 + r)) << 12) + (head << 8) + (s << 3);
        bf16x8 v = *(const bf16x8*)src;
        *(bf16x8*)(sA + r * 512 + ((s ^ (r & 31)) << 4)) = v;
    }
    __syncthreads();

    int wr = wave & 1;   // owns row-blocks {2wr, 2wr+1} in GEMM1
    int wm = wave >> 1;  // owns m-blocks {4wm..4wm+3} in GEMM1

    f32x4 acc[4][4] = {};   // [rb][cb] out rows x d accum

    for (int mc = 0; mc < 8; ++mc) {
        int m0 = mc << 7;   // 128-wide M chunk

        // ---- GEMM1: H^T fragments = mfma(W1-frag, X-frag) ----
        f32x4 hacc[4][2] = {};
        #pragma unroll
        for (int ks = 0; ks < 8; ++ks) {
            bf16x8 xb[2];
            #pragma unroll
            for (int j = 0; j < 2; ++j) {
                int r = ((2 * wr + j) << 4) + l15;
                int bo = r * 512 + ((((ks << 6) + (lq << 4))) ^ ((r & 31) << 4));
                xb[j] = *(const bf16x8*)(sA + bo);
            }
            bf16x8 wf[4];
            int kk = (ks << 5) + (lq << 3);
            #pragma unroll
            for (int i = 0; i < 4; ++i) {
                int m = m0 + (((wm << 2) + i) << 4) + l15;
                wf[i] = *(const bf16x8*)(upT + ((size_t)((head << 10) + m) << 8) + kk);
            }
            __builtin_amdgcn_s_setprio(1);
            #pragma unroll
            for (int i = 0; i < 4; ++i)
                #pragma unroll
                for (int j = 0; j < 2; ++j)
                    hacc[i][j] = __builtin_amdgcn_mfma_f32_16x16x32_bf16(wf[i], xb[j], hacc[i][j], 0, 0, 0);
            __builtin_amdgcn_s_setprio(0);
        }
        // gelu + write hidden (lane holds 4 consecutive m for fixed row -> b64 write)
        #pragma unroll
        for (int i = 0; i < 4; ++i) {
            #pragma unroll
            for (int j = 0; j < 2; ++j) {
                int r = ((2 * wr + j) << 4) + l15;
                int mbyte = (((wm << 2) + i) << 5) + (lq << 3);
                float g0 = gelu_fast(hacc[i][j][0]);
                float g1 = gelu_fast(hacc[i][j][1]);
                float g2 = gelu_fast(hacc[i][j][2]);
                float g3 = gelu_fast(hacc[i][j][3]);
                uint2 wv;
                wv.x = f2bf(g0) | ((unsigned int)f2bf(g1) << 16);
                wv.y = f2bf(g2) | ((unsigned int)f2bf(g3) << 16);
                *(uint2*)(sH + r * 256 + (mbyte ^ ((r & 15) << 4))) = wv;
            }
        }
        __syncthreads();

        // ---- GEMM2: acc += H(64x128) * W2chunk(128x256), W2 frags from L2 ----
        #pragma unroll
        for (int ks = 0; ks < 4; ++ks) {
            bf16x8 ha[4];
            #pragma unroll
            for (int rb = 0; rb < 4; ++rb) {
                int r = (rb << 4) + l15;
                int bo = r * 256 + ((((ks << 6) + (lq << 4))) ^ ((r & 15) << 4));
                ha[rb] = *(const bf16x8*)(sH + bo);
            }
            bf16x8 wf[4];
            int mg = m0 + (ks << 5) + (lq << 3);
            #pragma unroll
            for (int i = 0; i < 4; ++i) {
                int d = (((wave << 2) + i) << 4) + l15;
                wf[i] = *(const bf16x8*)(downT + ((size_t)((head << 8) + d) << 10) + mg);
            }
            __builtin_amdgcn_s_setprio(1);
            #pragma unroll
            for (int i = 0; i < 4; ++i)
                #pragma unroll
                for (int rb = 0; rb < 4; ++rb)
                    acc[rb][i] = __builtin_amdgcn_mfma_f32_16x16x32_bf16(ha[rb], wf[i], acc[rb][i], 0, 0, 0);
            __builtin_amdgcn_s_setprio(0);
        }
        __syncthreads();
    }

    // ---- epilogue: coalesced store into permuted-layout yP ----
    // acc[rb][i][e]: row = row0 + rb*16 + lq*4 + e, col = head*256 + (wave*4+i)*16 + l15
    if (YPF32) {
        float* yp = (float*)yPv;
        #pragma unroll
        for (int rb = 0; rb < 4; ++rb)
            #pragma unroll
            for (int i = 0; i < 4; ++i) {
                int rg = row0 + (rb << 4) + (lq << 2);
                int dc = (head << 8) + (((wave << 2) + i) << 4) + l15;
                #pragma unroll
                for (int e = 0; e < 4; ++e)
                    yp[((size_t)(rg + e) << 12) + dc] = acc[rb][i][e];
            }
    } else {
        unsigned short* yp = (unsigned short*)yPv;
        #pragma unroll
        for (int rb = 0; rb < 4; ++rb)
            #pragma unroll
            for (int i = 0; i < 4; ++i) {
                int rg = row0 + (rb << 4) + (lq << 2);
                int dc = (head << 8) + (((wave << 2) + i) << 4) + l15;
                #pragma unroll
                for (int e = 0; e < 4; ++e)
                    yp[((size_t)(rg + e) << 12) + dc] = f2bf(acc[rb][i][e]);
            }
    }
}

extern "C" void kernel_launch(void* const* d_in, const int* in_sizes, int n_in,
                              void* d_out, int out_size, void* d_ws, size_t ws_size,
                              hipStream_t stream) {
    const float* x    = (const float*)d_in[0];   // (4,2048,4096) f32
    const float* up   = (const float*)d_in[1];   // (16,256,1024) f32
    const float* down = (const float*)d_in[2];   // (16,1024,256) f32
    const int*   perm = (const int*)d_in[3];     // (4096,) i32
    float* out = (float*)d_out;

    const size_t W = (size_t)16 * 1024 * 256;    // weight elements per matrix
    const size_t XN = (size_t)8192 * 4096;       // activation elements
    unsigned short* upT   = (unsigned short*)d_ws;
    unsigned short* downT = upT + W;
    unsigned short* xP    = downT + W;
    void* yP = (void*)(xP + XN);
    size_t base_bytes = (2 * W + XN) * 2;        // 83.9 MB
    bool ypf32 = ws_size >= base_bytes + XN * 4; // need 218 MB for f32 yP, else bf16 (151 MB)

    transpose_cvt_kernel<<<16 * 4 * 16, 256, 0, stream>>>(up, upT, 256, 1024);
    transpose_cvt_kernel<<<16 * 16 * 4, 256, 0, stream>>>(down, downT, 1024, 256);
    permute_x_kernel<<<2048, 256, 0, stream>>>(x, perm, xP);

    if (ypf32) {
        ffn_kernel<1><<<2048, 256, 0, stream>>>(xP, upT, downT, yP);
        unpermute_kernel<1><<<2048, 256, 0, stream>>>(yP, perm, out);
    } else {
        ffn_kernel<0><<<2048, 256, 0, stream>>>(xP, upT, downT, yP);
        unpermute_kernel<0><<<2048, 256, 0, stream>>>(yP, perm, out);
    }
}

// Round 9
// 561.853 us; speedup vs baseline: 2.2755x; 1.1732x over previous
//
#include <hip/hip_runtime.h>
#include <hip/hip_bf16.h>
#include <math.h>

// SparseFeedForward: B=4 L=2048 H=16 Dh=256 M=1024, D=4096, rows=8192
// out[r, perm[h*256+d]] = sum_m gelu( sum_k x[r, perm[h*256+k]] * up[h,k,m] ) * down[h,m,d]
//
// v5: v4 + (a) no-dup GEMM1 wave decomposition (wave owns 2 m-blocks x 4 row-blocks;
//     halves GEMM1 L2 weight traffic), (b) 1-deep register prefetch of weight frags in
//     both GEMMs, (c) GEMM2 batch-0 weight loads issued before the barrier (latency
//     hides under gelu + barrier drain). Aux kernels unchanged.

typedef __attribute__((ext_vector_type(8))) short bf16x8;
typedef __attribute__((ext_vector_type(4))) float f32x4;

__device__ __forceinline__ unsigned short f2bf(float f) {
    unsigned int u = __builtin_bit_cast(unsigned int, f);
    u = (u + 0x7FFFu + ((u >> 16) & 1u)) >> 16;   // RNE
    return (unsigned short)u;
}
__device__ __forceinline__ float bf2f(unsigned short u) {
    return __builtin_bit_cast(float, ((unsigned int)u) << 16);
}

// gelu(x) ~= x * sigmoid(2*0.79788456*(x + 0.044715 x^3)); sigmoid via exp2/rcp.
__device__ __forceinline__ float gelu_fast(float x) {
    float x2 = x * x;
    float a = x * __builtin_fmaf(-0.10294437f, x2, -2.3022082f); // -2u*log2(e)
    return x * __builtin_amdgcn_rcpf(1.0f + __builtin_amdgcn_exp2f(a));
}

// dst[h][c][r] = bf16(src[h][r][c])   (per-head transpose-convert)
__global__ __launch_bounds__(256) void transpose_cvt_kernel(
        const float* __restrict__ src, unsigned short* __restrict__ dst,
        int R, int C) {
    int tilesC = C >> 6;
    int tiles = tilesC * (R >> 6);
    int h = blockIdx.x / tiles;
    int t = blockIdx.x % tiles;
    int r0 = (t / tilesC) << 6;
    int c0 = (t % tilesC) << 6;
    const float* s = src + (size_t)h * R * C;
    unsigned short* d = dst + (size_t)h * R * C;
    __shared__ float tl[64][65];
    int col = threadIdx.x & 63;
    int rr = threadIdx.x >> 6;
    #pragma unroll
    for (int i = 0; i < 16; ++i) {
        int row = (i << 2) + rr;
        tl[row][col] = s[(size_t)(r0 + row) * C + (c0 + col)];
    }
    __syncthreads();
    #pragma unroll
    for (int i = 0; i < 16; ++i) {
        int row = (i << 2) + rr;
        d[(size_t)(c0 + row) * R + (r0 + col)] = f2bf(tl[col][row]);
    }
}

// xP[r][j] = bf16(x[r][perm[j]]) — 4 rows/block, bf16 LDS rows, one barrier
__global__ __launch_bounds__(256) void permute_x_kernel(
        const float* __restrict__ x, const int* __restrict__ perm,
        unsigned short* __restrict__ xP) {
    __shared__ unsigned short rbf[4][4096];   // 32 KB
    __shared__ int sperm[4096];               // 16 KB
    int tid = threadIdx.x;
    #pragma unroll
    for (int i = 0; i < 16; ++i) sperm[(i << 8) + tid] = perm[(i << 8) + tid];
    size_t r0 = (size_t)blockIdx.x << 2;
    #pragma unroll
    for (int rr = 0; rr < 4; ++rr) {
        const float4* xr = (const float4*)(x + ((r0 + rr) << 12));
        #pragma unroll
        for (int i = 0; i < 4; ++i) {
            float4 v = xr[(i << 8) + tid];
            int j = ((i << 8) + tid) << 2;
            uint2 wv;
            wv.x = f2bf(v.x) | ((unsigned int)f2bf(v.y) << 16);
            wv.y = f2bf(v.z) | ((unsigned int)f2bf(v.w) << 16);
            *(uint2*)(&rbf[rr][j]) = wv;
        }
    }
    __syncthreads();
    #pragma unroll
    for (int rr = 0; rr < 4; ++rr) {
        alignas(16) unsigned short tmp[16];
        int j0 = tid << 4;
        #pragma unroll
        for (int i = 0; i < 16; ++i) tmp[i] = rbf[rr][sperm[j0 + i]];
        *(uint4*)(xP + ((r0 + rr) << 12) + j0) = *(const uint4*)tmp;
        *(uint4*)(xP + ((r0 + rr) << 12) + j0 + 8) = *(const uint4*)(tmp + 8);
    }
}

// out[r][perm[j]] = yP[r][j] — 4 rows/block, scatter into LDS, coalesced out
template<int F32>
__global__ __launch_bounds__(256) void unpermute_kernel(
        const void* __restrict__ yPv, const int* __restrict__ perm,
        float* __restrict__ out) {
    __shared__ float rows[4][4096];   // 64 KB
    __shared__ int sperm[4096];       // 16 KB
    int tid = threadIdx.x;
    #pragma unroll
    for (int i = 0; i < 16; ++i) sperm[(i << 8) + tid] = perm[(i << 8) + tid];
    size_t r0 = (size_t)blockIdx.x << 2;
    int j0 = tid << 4;
    float vals[4][16];
    #pragma unroll
    for (int rr = 0; rr < 4; ++rr) {
        if (F32) {
            const float4* yr = (const float4*)((const float*)yPv + ((r0 + rr) << 12) + j0);
            #pragma unroll
            for (int i = 0; i < 4; ++i) {
                float4 v = yr[i];
                vals[rr][4 * i] = v.x; vals[rr][4 * i + 1] = v.y;
                vals[rr][4 * i + 2] = v.z; vals[rr][4 * i + 3] = v.w;
            }
        } else {
            const uint2* yr = (const uint2*)((const unsigned short*)yPv + ((r0 + rr) << 12) + j0);
            #pragma unroll
            for (int i = 0; i < 4; ++i) {
                uint2 v = yr[i];
                vals[rr][4 * i]     = bf2f((unsigned short)(v.x & 0xffffu));
                vals[rr][4 * i + 1] = bf2f((unsigned short)(v.x >> 16));
                vals[rr][4 * i + 2] = bf2f((unsigned short)(v.y & 0xffffu));
                vals[rr][4 * i + 3] = bf2f((unsigned short)(v.y >> 16));
            }
        }
    }
    __syncthreads();   // sperm ready
    #pragma unroll
    for (int rr = 0; rr < 4; ++rr)
        #pragma unroll
        for (int i = 0; i < 16; ++i)
            rows[rr][sperm[j0 + i]] = vals[rr][i];
    __syncthreads();
    #pragma unroll
    for (int rr = 0; rr < 4; ++rr) {
        float4* orow = (float4*)(out + ((r0 + rr) << 12));
        #pragma unroll
        for (int i = 0; i < 4; ++i)
            orow[(i << 8) + tid] = *(const float4*)(&rows[rr][((i << 8) + tid) << 2]);
    }
}

template<int YPF32>
__global__ __launch_bounds__(256, 3) void ffn_kernel(
    const unsigned short* __restrict__ xP,     // [8192][4096] bf16, permuted cols
    const unsigned short* __restrict__ upT,    // [16][1024 m][256 k] bf16
    const unsigned short* __restrict__ downT,  // [16][256 d][1024 m] bf16
    void* __restrict__ yPv)                    // [8192][4096] f32 or bf16, permuted cols
{
    __shared__ unsigned char sA[64 * 512];   // X tile [64 r][256 k] bf16, XOR-swizzled (32 cells/row)
    __shared__ unsigned char sH[64 * 256];   // hidden [64 r][128 m] bf16, XOR-swizzled (16 cells/row)

    int tid = threadIdx.x;
    int lane = tid & 63;
    int wave = tid >> 6;
    int l15 = lane & 15;
    int lq = lane >> 4;

    // XCD-chunk swizzle: 2048 blocks, 8 XCDs; head-major within chunk (<=2 heads/XCD in L2)
    int bid = blockIdx.x;
    int nb = ((bid & 7) << 8) + (bid >> 3);
    int head = nb >> 7;
    int row0 = (nb & 127) << 6;

    const unsigned short* upH = upT + ((size_t)head << 18);    // head*1024*256
    const unsigned short* dnH = downT + ((size_t)head << 18);  // head*256*1024

    // ---- stage A: linear coalesced read from xP head-slice -> swizzled LDS ----
    #pragma unroll
    for (int i = 0; i < 8; ++i) {
        int idx = tid + (i << 8);            // 0..2047 cells of 16B
        int r = idx >> 5;                    // row 0..63
        int s = idx & 31;                    // linear source cell
        const unsigned short* src = xP + (((size_t)(row0 + r)) << 12) + (head << 8) + (s << 3);
        bf16x8 v = *(const bf16x8*)src;
        *(bf16x8*)(sA + r * 512 + ((s ^ (r & 31)) << 4)) = v;
    }
    __syncthreads();

    // GEMM1: wave owns m-blocks {2*wave, 2*wave+1} (no duplication), all 4 row-blocks.
    int mrow0 = (wave << 5) + l15;   // m-row within chunk for jm=0 (jm=1 is +16)
    int kk0 = lq << 3;

    f32x4 acc[4][4] = {};   // [rb][dc] out rows x d accum (AGPR)

    // prologue prefetch: GEMM1 weights for (mc=0, ks=0)
    bf16x8 w1n0, w1n1;
    {
        const unsigned short* p = upH + (size_t)mrow0 * 256 + kk0;
        w1n0 = *(const bf16x8*)p;
        w1n1 = *(const bf16x8*)(p + 16 * 256);
    }

    for (int mc = 0; mc < 8; ++mc) {
        int m0 = mc << 7;   // 128-wide M chunk

        // ---- GEMM1: H^T fragments = mfma(W1-frag, X-frag), 1-deep prefetch ----
        f32x4 hacc[2][4] = {};
        #pragma unroll
        for (int ks = 0; ks < 8; ++ks) {
            bf16x8 w1c0 = w1n0, w1c1 = w1n1;
            {   // prefetch next ks (or next mc's ks=0)
                int nks = (ks + 1) & 7;
                int nm0 = (ks == 7) ? (((mc + 1) & 7) << 7) : m0;
                const unsigned short* p = upH + (size_t)(nm0 + mrow0) * 256 + (nks << 5) + kk0;
                w1n0 = *(const bf16x8*)p;
                w1n1 = *(const bf16x8*)(p + 16 * 256);
            }
            bf16x8 xb[4];
            #pragma unroll
            for (int rb = 0; rb < 4; ++rb) {
                int r = (rb << 4) + l15;
                xb[rb] = *(const bf16x8*)(sA + r * 512 + (((ks << 6) + (lq << 4)) ^ ((r & 31) << 4)));
            }
            __builtin_amdgcn_s_setprio(1);
            #pragma unroll
            for (int rb = 0; rb < 4; ++rb) {
                hacc[0][rb] = __builtin_amdgcn_mfma_f32_16x16x32_bf16(w1c0, xb[rb], hacc[0][rb], 0, 0, 0);
                hacc[1][rb] = __builtin_amdgcn_mfma_f32_16x16x32_bf16(w1c1, xb[rb], hacc[1][rb], 0, 0, 0);
            }
            __builtin_amdgcn_s_setprio(0);
        }

        // gelu + write hidden: tile (mb=2*wave+jm, rb); lane holds 4 consecutive m
        #pragma unroll
        for (int jm = 0; jm < 2; ++jm) {
            int mbyte = (((wave << 1) + jm) << 5) + (lq << 3);
            #pragma unroll
            for (int rb = 0; rb < 4; ++rb) {
                int r = (rb << 4) + l15;
                float g0 = gelu_fast(hacc[jm][rb][0]);
                float g1 = gelu_fast(hacc[jm][rb][1]);
                float g2 = gelu_fast(hacc[jm][rb][2]);
                float g3 = gelu_fast(hacc[jm][rb][3]);
                uint2 wv;
                wv.x = f2bf(g0) | ((unsigned int)f2bf(g1) << 16);
                wv.y = f2bf(g2) | ((unsigned int)f2bf(g3) << 16);
                *(uint2*)(sH + r * 256 + (mbyte ^ ((r & 15) << 4))) = wv;
            }
        }

        // issue GEMM2 batch-0 weight loads BEFORE the barrier (hide under drain)
        bf16x8 wf2[4];
        {
            int mg = m0 + kk0;   // ks2 = 0
            #pragma unroll
            for (int i = 0; i < 4; ++i) {
                int d = (((wave << 2) + i) << 4) + l15;
                wf2[i] = *(const bf16x8*)(dnH + (size_t)d * 1024 + mg);
            }
        }
        __syncthreads();

        // ---- GEMM2: acc += H(64x128) * W2chunk(128x256), 1-deep prefetch ----
        #pragma unroll
        for (int ks = 0; ks < 4; ++ks) {
            bf16x8 ha[4];
            #pragma unroll
            for (int rb = 0; rb < 4; ++rb) {
                int r = (rb << 4) + l15;
                ha[rb] = *(const bf16x8*)(sH + r * 256 + (((ks << 6) + (lq << 4)) ^ ((r & 15) << 4)));
            }
            bf16x8 wcur[4];
            #pragma unroll
            for (int i = 0; i < 4; ++i) wcur[i] = wf2[i];
            if (ks < 3) {
                int mg = m0 + ((ks + 1) << 5) + kk0;
                #pragma unroll
                for (int i = 0; i < 4; ++i) {
                    int d = (((wave << 2) + i) << 4) + l15;
                    wf2[i] = *(const bf16x8*)(dnH + (size_t)d * 1024 + mg);
                }
            }
            __builtin_amdgcn_s_setprio(1);
            #pragma unroll
            for (int i = 0; i < 4; ++i)
                #pragma unroll
                for (int rb = 0; rb < 4; ++rb)
                    acc[rb][i] = __builtin_amdgcn_mfma_f32_16x16x32_bf16(ha[rb], wcur[i], acc[rb][i], 0, 0, 0);
            __builtin_amdgcn_s_setprio(0);
        }
        __syncthreads();
    }

    // ---- epilogue: coalesced store into permuted-layout yP ----
    // acc[rb][i][e]: row = row0 + rb*16 + lq*4 + e, col = head*256 + (wave*4+i)*16 + l15
    if (YPF32) {
        float* yp = (float*)yPv;
        #pragma unroll
        for (int rb = 0; rb < 4; ++rb)
            #pragma unroll
            for (int i = 0; i < 4; ++i) {
                int rg = row0 + (rb << 4) + (lq << 2);
                int dc = (head << 8) + (((wave << 2) + i) << 4) + l15;
                #pragma unroll
                for (int e = 0; e < 4; ++e)
                    yp[((size_t)(rg + e) << 12) + dc] = acc[rb][i][e];
            }
    } else {
        unsigned short* yp = (unsigned short*)yPv;
        #pragma unroll
        for (int rb = 0; rb < 4; ++rb)
            #pragma unroll
            for (int i = 0; i < 4; ++i) {
                int rg = row0 + (rb << 4) + (lq << 2);
                int dc = (head << 8) + (((wave << 2) + i) << 4) + l15;
                #pragma unroll
                for (int e = 0; e < 4; ++e)
                    yp[((size_t)(rg + e) << 12) + dc] = f2bf(acc[rb][i][e]);
            }
    }
}

extern "C" void kernel_launch(void* const* d_in, const int* in_sizes, int n_in,
                              void* d_out, int out_size, void* d_ws, size_t ws_size,
                              hipStream_t stream) {
    const float* x    = (const float*)d_in[0];   // (4,2048,4096) f32
    const float* up   = (const float*)d_in[1];   // (16,256,1024) f32
    const float* down = (const float*)d_in[2];   // (16,1024,256) f32
    const int*   perm = (const int*)d_in[3];     // (4096,) i32
    float* out = (float*)d_out;

    const size_t W = (size_t)16 * 1024 * 256;    // weight elements per matrix
    const size_t XN = (size_t)8192 * 4096;       // activation elements
    unsigned short* upT   = (unsigned short*)d_ws;
    unsigned short* downT = upT + W;
    unsigned short* xP    = downT + W;
    void* yP = (void*)(xP + XN);
    size_t base_bytes = (2 * W + XN) * 2;        // 83.9 MB
    bool ypf32 = ws_size >= base_bytes + XN * 4; // need 218 MB for f32 yP, else bf16 (151 MB)

    transpose_cvt_kernel<<<16 * 4 * 16, 256, 0, stream>>>(up, upT, 256, 1024);
    transpose_cvt_kernel<<<16 * 16 * 4, 256, 0, stream>>>(down, downT, 1024, 256);
    permute_x_kernel<<<2048, 256, 0, stream>>>(x, perm, xP);

    if (ypf32) {
        ffn_kernel<1><<<2048, 256, 0, stream>>>(xP, upT, downT, yP);
        unpermute_kernel<1><<<2048, 256, 0, stream>>>(yP, perm, out);
    } else {
        ffn_kernel<0><<<2048, 256, 0, stream>>>(xP, upT, downT, yP);
        unpermute_kernel<0><<<2048, 256, 0, stream>>>(yP, perm, out);
    }
}